// Round 13
// baseline (125.890 us; speedup 1.0000x reference)
//
#include <hip/hip_runtime.h>
#include <hip/hip_fp16.h>

typedef _Float16 f16;
typedef _Float16 f16x8 __attribute__((ext_vector_type(8)));
typedef float f32x4 __attribute__((ext_vector_type(4)));
typedef float f32x16 __attribute__((ext_vector_type(16)));
typedef unsigned u32x4 __attribute__((ext_vector_type(4)));

#define AS1(p) ((const __attribute__((address_space(1))) void*)(p))
#define AS3(p) ((__attribute__((address_space(3))) void*)(p))

__device__ __forceinline__ void gload16(const void* g, void* l) {
  __builtin_amdgcn_global_load_lds(AS1(g), AS3(l), 16, 0, 0);
}

__device__ __forceinline__ float sgm(float x) {
  // sigmoid(16*x) = 1/(1+2^(-16*log2e*x))
  return __builtin_amdgcn_rcpf(1.0f + __builtin_amdgcn_exp2f(x * -23.083120654223414f));
}

__device__ __forceinline__ unsigned pk2(float a, float b) {
  return __builtin_bit_cast(unsigned, __builtin_amdgcn_cvt_pkrtz(a, b));
}

// ---------------------------------------------------------------------------
// Tiled transpose + f32->f16 convert body: 64x64 tile.
// ---------------------------------------------------------------------------
__device__ __forceinline__ void tbody(const float* __restrict__ ip,
                                      f16* __restrict__ op,
                                      long in_rs, long out_rs) {
  __shared__ float t[64][68];
  int tid = threadIdx.x;
  {
    int c4 = (tid & 15) * 4, r0 = tid >> 4;
#pragma unroll
    for (int p = 0; p < 4; ++p) {
      int r = r0 + 16 * p;
      float4 v = *(const float4*)(ip + (long)r * in_rs + c4);
      t[c4 + 0][r] = v.x; t[c4 + 1][r] = v.y; t[c4 + 2][r] = v.z; t[c4 + 3][r] = v.w;
    }
  }
  __syncthreads();
  {
    int r4 = (tid & 15) * 4, c0 = tid >> 4;
#pragma unroll
    for (int p = 0; p < 4; ++p) {
      int c = c0 + 16 * p;
      float4 v = *(const float4*)(&t[c][r4]);
      union { f16 h[4]; unsigned long long u; } pk;
      pk.h[0] = (f16)v.x; pk.h[1] = (f16)v.y; pk.h[2] = (f16)v.z; pk.h[3] = (f16)v.w;
      *(unsigned long long*)(op + (long)c * out_rs + r4) = pk.u;
    }
  }
}

// All input transposes in one launch. Flat grid 1024 blocks.
__global__ __launch_bounds__(256) void tall(
    const float* __restrict__ qin, const float* __restrict__ kvin,
    const float* __restrict__ Wq, const float* __restrict__ Wk,
    const float* __restrict__ Wv, const float* __restrict__ Wz,
    f16* __restrict__ Xq, f16* __restrict__ Xkv,
    f16* __restrict__ Wqt, f16* __restrict__ Wkt, f16* __restrict__ Wvt,
    f16* __restrict__ Wzt) {
  int id = blockIdx.x;
  if (id < 512) {
    int x = id & 15, y = (id >> 4) & 3, z = id >> 6;
    const float* in = (z < 4) ? qin : kvin;
    f16* out = (z < 4) ? Xq : Xkv;
    long b = z & 3;
    tbody(in + b * 262144 + (long)(y * 64) * 1024 + x * 64,
          out + b * 262144 + (long)(x * 64) * 256 + y * 64, 1024, 256);
  } else if (id < 896) {
    int t = id - 512;
    int x = t & 31, y = (t >> 5) & 3, z = t >> 7;
    const float* in = (z == 0) ? Wq : (z == 1) ? Wk : Wv;
    f16* out = (z == 0) ? Wqt : (z == 1) ? Wkt : Wvt;
    tbody(in + (long)(y * 64) * 2048 + x * 64,
          out + (long)(x * 64) * 256 + y * 64, 2048, 256);
  } else {
    int t = id - 896;
    int x = t & 3, y = (t >> 2) & 3;
    long z = t >> 4;
    tbody(Wz + z * 256 + (long)(y * 64) * 2048 + x * 64,
          Wzt + z * 256 + (long)(x * 64) * 2048 + y * 64, 2048, 2048);
  }
}

// ---------------------------------------------------------------------------
// QKV projection, double-buffered staging. BM=BN=128, BK=64.
// z=0: Q -> Qh[b][h][s][fi]; z=1: K -> Kh; z=2: V -> Vt[b][h][fi][s]
// grid (32,16,3), 256 threads.  (r7-validated)
// ---------------------------------------------------------------------------
__global__ __launch_bounds__(256) void projk(
    const f16* __restrict__ Xq, const f16* __restrict__ Xkv,
    const f16* __restrict__ Wqt, const f16* __restrict__ Wkt, const f16* __restrict__ Wvt,
    f16* __restrict__ Qh, f16* __restrict__ Kh, f16* __restrict__ Vt) {
  __shared__ char sm[65536];
  int z = blockIdx.z;
  const f16* A = (z == 0) ? Xq : Xkv;
  const f16* B = (z == 0) ? Wqt : (z == 1) ? Wkt : Wvt;
  int m0 = blockIdx.x * 128, n0 = blockIdx.y * 128;
  int tid = threadIdx.x, wave = tid >> 6, lane = tid & 63;
  int wm = wave & 1, wn = wave >> 1;
  f32x4 acc[4][4];
#pragma unroll
  for (int i = 0; i < 4; ++i)
#pragma unroll
    for (int j = 0; j < 4; ++j) acc[i][j] = (f32x4){0.f, 0.f, 0.f, 0.f};

  auto PSTAGE = [&](int buf, int kt) {
    char* As = sm + buf * 32768;
    char* Bs = As + 16384;
    int k0 = kt * 64;
#pragma unroll
    for (int is = 0; is < 4; ++is) {
      int loff = is * 4096 + wave * 1024;
      int g = loff + lane * 16;
      int row = g >> 7, sl = (g >> 4) & 7;
      int sp = (sl ^ (row & 7)) * 8;
      gload16(A + (long)(m0 + row) * 256 + k0 + sp, As + loff);
      gload16(B + (long)(n0 + row) * 256 + k0 + sp, Bs + loff);
    }
  };

  PSTAGE(0, 0);
  __syncthreads();
  for (int kt = 0; kt < 4; ++kt) {
    int cur = kt & 1;
    if (kt < 3) PSTAGE(cur ^ 1, kt + 1);
    const char* As = sm + cur * 32768;
    const char* Bs = As + 16384;
#pragma unroll
    for (int t = 0; t < 2; ++t) {
      f16x8 af[4], bf[4];
#pragma unroll
      for (int mi = 0; mi < 4; ++mi) {
        int row = wm * 64 + mi * 16 + (lane & 15);
        int sl = (t * 4 + (lane >> 4)) ^ (row & 7);
        af[mi] = *(const f16x8*)(As + row * 128 + sl * 16);
      }
#pragma unroll
      for (int ni = 0; ni < 4; ++ni) {
        int row = wn * 64 + ni * 16 + (lane & 15);
        int sl = (t * 4 + (lane >> 4)) ^ (row & 7);
        bf[ni] = *(const f16x8*)(Bs + row * 128 + sl * 16);
      }
#pragma unroll
      for (int mi = 0; mi < 4; ++mi)
#pragma unroll
        for (int ni = 0; ni < 4; ++ni)
          acc[mi][ni] = __builtin_amdgcn_mfma_f32_16x16x32_f16(af[mi], bf[ni], acc[mi][ni], 0, 0, 0);
    }
    __syncthreads();
  }
#pragma unroll
  for (int mi = 0; mi < 4; ++mi)
#pragma unroll
    for (int ni = 0; ni < 4; ++ni) {
      int cc = wn * 64 + ni * 16 + (lane & 15);
      int rs0 = wm * 64 + mi * 16 + (lane >> 4) * 4;
      union { f16 h[4]; unsigned long long u; } pk;
#pragma unroll
      for (int r = 0; r < 4; ++r) pk.h[r] = (f16)acc[mi][ni][r];
      *(unsigned long long*)(sm + cc * 272 + rs0 * 2) = pk.u;
    }
  __syncthreads();
  if (z < 2) {
    f16* outp = (z == 0) ? Qh : Kh;
#pragma unroll
    for (int pass = 0; pass < 4; ++pass) {
      int item = pass * 256 + tid;
      int rs = item & 127, h = item >> 7;
      int m = m0 + rs, b = m >> 10, s = m & 1023;
      union { unsigned short u16[16]; uint4 q[2]; } pk;
#pragma unroll
      for (int u = 0; u < 16; ++u)
        pk.u16[u] = *(const unsigned short*)(sm + (h + 8 * u) * 272 + rs * 2);
      f16* dst = outp + ((long)(b * 8 + h) * 1024 + s) * 256 + (n0 >> 3);
      *(uint4*)dst = pk.q[0];
      *(uint4*)(dst + 8) = pk.q[1];
    }
  } else {
    int cc = tid >> 1, half = tid & 1;
    int c = n0 + cc, h = c & 7, fi = c >> 3;
    int m = m0 + half * 64;
    int b = m >> 10, s0 = m & 1023;
    uint4 q[8];
#pragma unroll
    for (int j = 0; j < 8; ++j)
      q[j] = *(const uint4*)(sm + cc * 272 + half * 128 + j * 16);
    f16* dst = Vt + ((long)(b * 8 + h) * 256 + fi) * 1024 + s0;
#pragma unroll
    for (int j = 0; j < 8; ++j) *(uint4*)(dst + j * 8) = q[j];
  }
}

// ---------------------------------------------------------------------------
// Fused attention v8: r5's VALIDATED 32x32 kernel (2-wave/128t blocks,
// KVBLK=32, dbuf, q[16] frags, swapped QK, sigmoid+pk2, 4x permlane32
// redistribution, A0/A1 PV, direct-store epilogue, K [32r][32slot] slot^row)
// with ONE change: V uses r7's validated [f][4-slot] slot=jc^((f>>1)&3)
// layout+stage (64B-contiguous segments, 4x fewer VMEM requests than r5's
// chunk-major), with the PV read adapted to that layout (the only
// unvalidated formula in this kernel).
// Zb aliases Qh (blocks write only their own Q rows). grid 512, 128 threads.
// ---------------------------------------------------------------------------
__global__ __launch_bounds__(128) void attnk(
    const f16* __restrict__ Qh, const f16* __restrict__ Kh,
    const f16* __restrict__ Vt, f16* __restrict__ Zb) {
  __shared__ char sm[65536];  // 2 x (K 16KB + V 16KB)
  int flat = blockIdx.x;
  int xcd = flat & 7, slotb = flat >> 3;
  int bh = xcd + 8 * (slotb & 3);   // 4 heads per XCD -> K/V L2-resident
  int i0 = (slotb >> 2) * 64;
  int tid = threadIdx.x, wave = tid >> 6, lane = tid & 63;
  int l31 = lane & 31, l5 = lane >> 5;
  const f16* Qp = Qh + (long)bh * 262144;
  const f16* Kp = Kh + (long)bh * 262144;
  const f16* Vp = Vt + (long)bh * 262144;
  int iw = i0 + wave * 32;

  auto STAGE = [&](int ob, int j0) {
#pragma unroll
    for (int r = 0; r < 8; ++r) {
      int o = r * 2048 + tid * 16;
      {  // K (r5-exact): [32 rows][32 slots], slot sl holds chunk sl^row
        int row = o >> 9, sl = (o >> 4) & 31;
        gload16(Kp + (long)(j0 + row) * 256 + ((sl ^ row) * 8), sm + ob + o);
      }
      {  // V (r7-exact family): [256f][4 slots], slot sl holds jc = sl^((f>>1)&3)
        int f = o >> 6, sl = (o >> 4) & 3;
        int jc = sl ^ ((f >> 1) & 3);
        gload16(Vp + (long)f * 1024 + j0 + jc * 8, sm + ob + 16384 + o);
      }
    }
  };

  STAGE(0, 0);
  // Q B-frags (r5-exact): q[t] = Q[iw + l31][k = t*16 + l5*8 .. +8]
  f16x8 q[16];
  {
    const f16* qr = Qp + (long)(iw + l31) * 256 + l5 * 8;
#pragma unroll
    for (int t = 0; t < 16; ++t) q[t] = *(const f16x8*)(qr + t * 16);
  }
  f32x16 acc[8];
#pragma unroll
  for (int n = 0; n < 8; ++n)
    acc[n] = (f32x16){0.f,0.f,0.f,0.f,0.f,0.f,0.f,0.f,0.f,0.f,0.f,0.f,0.f,0.f,0.f,0.f};

  const int vkey = (l31 >> 1) & 3;
  __syncthreads();
  int bb = 0;
  for (int jt = 0; jt < 32; ++jt) {
    if (jt < 31) STAGE(bb ^ 32768, (jt + 1) * 32);
    const char* Ks = sm + bb;
    const char* Vs = sm + bb + 16384;
    // QK^T swapped (r5-exact): lane holds i = l31, j = (r&3)+8*(r>>2)+4*l5
    f32x16 s = (f32x16){0.f,0.f,0.f,0.f,0.f,0.f,0.f,0.f,0.f,0.f,0.f,0.f,0.f,0.f,0.f,0.f};
    __builtin_amdgcn_s_setprio(1);
#pragma unroll
    for (int t = 0; t < 16; ++t) {
      int c = 2 * t + l5;
      f16x8 kf = *(const f16x8*)(Ks + l31 * 512 + ((c ^ l31) * 16));
      s = __builtin_amdgcn_mfma_f32_32x32x16_f16(kf, q[t], s, 0, 0, 0);
    }
    __builtin_amdgcn_s_setprio(0);
    // sigmoid + pack (r5-exact)
    unsigned u[8];
#pragma unroll
    for (int c2 = 0; c2 < 8; ++c2) u[c2] = pk2(sgm(s[2 * c2]), sgm(s[2 * c2 + 1]));
    // redistribute to PV A-frags (r5-exact)
    auto w0 = __builtin_amdgcn_permlane32_swap(u[0], u[2], false, false);
    auto w1 = __builtin_amdgcn_permlane32_swap(u[1], u[3], false, false);
    auto w2 = __builtin_amdgcn_permlane32_swap(u[4], u[6], false, false);
    auto w3 = __builtin_amdgcn_permlane32_swap(u[5], u[7], false, false);
    u32x4 A0w, A1w;
    A0w[0] = w0[0]; A0w[1] = w1[0]; A0w[2] = w0[1]; A0w[3] = w1[1];
    A1w[0] = w2[0]; A1w[1] = w3[0]; A1w[2] = w2[1]; A1w[3] = w3[1];
    f16x8 A0 = __builtin_bit_cast(f16x8, A0w);
    f16x8 A1 = __builtin_bit_cast(f16x8, A1w);
    // PV (adapted read): B-frag = V[f = n*32+l31][jc*8..+8], jc = l5 (A0),
    // 2+l5 (A1), at swizzled slot jc^vkey of the 64B f-row.
    __builtin_amdgcn_s_setprio(1);
#pragma unroll
    for (int n = 0; n < 8; ++n) {
      int fb = (n * 32 + l31) * 64;
      f16x8 v0 = *(const f16x8*)(Vs + fb + ((l5 ^ vkey) * 16));
      acc[n] = __builtin_amdgcn_mfma_f32_32x32x16_f16(A0, v0, acc[n], 0, 0, 0);
      f16x8 v1 = *(const f16x8*)(Vs + fb + (((2 + l5) ^ vkey) * 16));
      acc[n] = __builtin_amdgcn_mfma_f32_32x32x16_f16(A1, v1, acc[n], 0, 0, 0);
    }
    __builtin_amdgcn_s_setprio(0);
    __syncthreads();
    bb ^= 32768;
  }
  // epilogue (r5-exact direct stores): O[i][f], i-row from C-layout
  f16* zp = Zb + (long)bh * 262144;
#pragma unroll
  for (int n = 0; n < 8; ++n)
#pragma unroll
    for (int r = 0; r < 16; ++r) {
      int i = iw + (r & 3) + 8 * (r >> 2) + 4 * l5;
      int f = n * 32 + l31;
      zp[(long)i * 256 + f] = (f16)acc[n][r];
    }
}

// ---------------------------------------------------------------------------
// Output projection + ReLU, double-buffered, BK=128 (r11-validated).
// grid (4,16,4), 256 threads.
// ---------------------------------------------------------------------------
__global__ __launch_bounds__(256) void zkern(
    const f16* __restrict__ Wzt, const f16* __restrict__ Zb,
    float* __restrict__ out) {
  __shared__ char sm[65536];  // 2 x (16KB A + 16KB B)
  int fo0 = blockIdx.x * 64, s0 = blockIdx.y * 64, b = blockIdx.z;
  int tid = threadIdx.x, wave = tid >> 6, lane = tid & 63;
  int wm = wave & 1, wn = wave >> 1;
  f32x4 acc[2][2];
#pragma unroll
  for (int i = 0; i < 2; ++i)
#pragma unroll
    for (int j = 0; j < 2; ++j) acc[i][j] = (f32x4){0.f, 0.f, 0.f, 0.f};

  auto ZSTAGE = [&](int buf, int kt) {
    char* As = sm + buf * 32768;
    char* Bs = As + 16384;
    int k0 = kt * 128, h = k0 >> 8, fi0 = k0 & 255;
#pragma unroll
    for (int is = 0; is < 4; ++is) {
      int loff = is * 4096 + wave * 1024;
      int g = loff + lane * 16;
      int row = g >> 8, sl = (g >> 4) & 15;
      int sp = (sl ^ (row & 15)) * 8;
      gload16(Wzt + (long)(fo0 + row) * 2048 + k0 + sp, As + loff);
      gload16(Zb + ((long)(b * 8 + h) * 1024 + s0 + row) * 256 + fi0 + sp, Bs + loff);
    }
  };

  ZSTAGE(0, 0);
  __syncthreads();
  for (int kt = 0; kt < 16; ++kt) {
    int cur = kt & 1;
    if (kt < 15) ZSTAGE(cur ^ 1, kt + 1);
    const char* As = sm + cur * 32768;
    const char* Bs = As + 16384;
#pragma unroll
    for (int t = 0; t < 4; ++t) {
      f16x8 af[2], bf[2];
#pragma unroll
      for (int mi = 0; mi < 2; ++mi) {
        int row = wm * 32 + mi * 16 + (lane & 15);
        int sl = (t * 4 + (lane >> 4)) ^ (row & 15);
        af[mi] = *(const f16x8*)(As + row * 256 + sl * 16);
      }
#pragma unroll
      for (int ni = 0; ni < 2; ++ni) {
        int row = wn * 32 + ni * 16 + (lane & 15);
        int sl = (t * 4 + (lane >> 4)) ^ (row & 15);
        bf[ni] = *(const f16x8*)(Bs + row * 256 + sl * 16);
      }
#pragma unroll
      for (int mi = 0; mi < 2; ++mi)
#pragma unroll
        for (int ni = 0; ni < 2; ++ni)
          acc[mi][ni] = __builtin_amdgcn_mfma_f32_16x16x32_f16(af[mi], bf[ni], acc[mi][ni], 0, 0, 0);
    }
    __syncthreads();
  }
#pragma unroll
  for (int mi = 0; mi < 2; ++mi)
#pragma unroll
    for (int ni = 0; ni < 2; ++ni)
#pragma unroll
      for (int r = 0; r < 4; ++r) {
        int fo = fo0 + wm * 32 + mi * 16 + (lane >> 4) * 4 + r;
        int s = s0 + wn * 32 + ni * 16 + (lane & 15);
        float v = acc[mi][ni][r];
        out[((long)b * 256 + fo) * 1024 + s] = v > 0.f ? v : 0.f;
      }
}

extern "C" void kernel_launch(void* const* d_in, const int* in_sizes, int n_in,
                              void* d_out, int out_size, void* d_ws, size_t ws_size,
                              hipStream_t stream) {
  const float* qin = (const float*)d_in[0];
  const float* kvin = (const float*)d_in[1];
  const float* Wq = (const float*)d_in[2];
  const float* Wk = (const float*)d_in[3];
  const float* Wv = (const float*)d_in[4];
  const float* Wz = (const float*)d_in[5];
  float* out = (float*)d_out;
  char* ws = (char*)d_ws;
  const long MB = 1 << 20;
  f16* Xq  = (f16*)(ws + 0 * MB);
  f16* Xkv = (f16*)(ws + 2 * MB);
  f16* Wqt = (f16*)(ws + 4 * MB);
  f16* Wkt = (f16*)(ws + 5 * MB);
  f16* Wvt = (f16*)(ws + 6 * MB);
  f16* Wzt = (f16*)(ws + 7 * MB);
  f16* Qh  = (f16*)(ws + 8 * MB);   // 16MB, aliased by Zb
  f16* Kh  = (f16*)(ws + 24 * MB);  // 16MB
  f16* Vt  = (f16*)(ws + 40 * MB);  // 16MB
  f16* Zb  = Qh;
  dim3 blk(256);
  tall<<<dim3(1024), blk, 0, stream>>>(qin, kvin, Wq, Wk, Wv, Wz,
                                       Xq, Xkv, Wqt, Wkt, Wvt, Wzt);
  projk<<<dim3(32, 16, 3), blk, 0, stream>>>(Xq, Xkv, Wqt, Wkt, Wvt, Qh, Kh, Vt);
  attnk<<<dim3(512), dim3(128), 0, stream>>>(Qh, Kh, Vt, Zb);
  zkern<<<dim3(4, 16, 4), blk, 0, stream>>>(Wzt, Zb, out);
}